// Round 7
// baseline (265.803 us; speedup 1.0000x reference)
//
#include <hip/hip_runtime.h>
#include <stdint.h>

// Gaussian kernel matrix K[i][j] = exp(-||x_i-x_j||^2/2), X: [16384][64] fp32.
// R7 = R6 (full-line LDS-transpose stores, 223.9 us) +
//  - 64x32 wave tiles: acc 64->32, braw 64->32, b 32->16 VGPRs  => ~150 VGPR,
//    __launch_bounds__(256,3): 3 blocks/CU = 3 waves/SIMD (R6 had 2) so a 3rd
//    wave covers store-issue gaps while others compute.
//  - epilogue VALU trim: no fminf (off-diag arg <= -20, safe), diagonal
//    cmp/cndmask only in tiles whose row/col ranges overlap (uniform branch).
// Kept: inline f32->bf16 cvt, B prefetch issued BEFORE stores (vmcnt FIFO
// decoupling), VMEM-only sched_barrier, wave-private LDS transpose so each
// store is 8 rows x 128B full lines.

typedef __attribute__((ext_vector_type(8))) short s16x8;   // 8 bf16 (MFMA A/B frag)
typedef __attribute__((ext_vector_type(4))) float f32x4;

#define DDIM 64
#define JT 8
#define LROW 36   // LDS row stride in floats (32 data + 4 pad; 144B, 16B-aligned)
#define LOG2E      1.4426950408889634f   // 2c
#define HALF_LOG2E 0.7213475204444817f   // c ; K = exp2(-c||i||^2 - c||j||^2 + 2c dot)

// fp32 -> bf16 RNE on the bit pattern; accumulates rounded value^2 for norms.
__device__ inline short cvt1(float x, float& sq) {
  uint32_t u = __builtin_bit_cast(uint32_t, x);
  uint32_t r = (u + 0x7fffu + ((u >> 16) & 1u)) & 0xffff0000u;
  float hf = __builtin_bit_cast(float, r);
  sq += hf * hf;
  return (short)(r >> 16);
}

// Issue the 4 dwordx4 loads for one fragment row. Raw loads only.
__device__ inline void issue_row(const float* __restrict__ X, int row, int lq,
                                 f32x4 r[4]) {
  const f32x4* p = reinterpret_cast<const f32x4*>(X + (size_t)row * DDIM + lq * 8);
  const f32x4* q = reinterpret_cast<const f32x4*>(X + (size_t)row * DDIM + 32 + lq * 8);
  r[0] = p[0]; r[1] = p[1]; r[2] = q[0]; r[3] = q[1];
}

// Raw f32 row data -> bf16 MFMA fragments + premultiplied norm (-c*||x||^2).
__device__ inline void cvt_row(const f32x4 r[4], s16x8 h[2], float& hnorm) {
  float s = 0.f;
#pragma unroll
  for (int ks = 0; ks < 2; ++ks) {
    s16x8 hh;
    hh[0] = cvt1(r[2*ks][0], s);   hh[1] = cvt1(r[2*ks][1], s);
    hh[2] = cvt1(r[2*ks][2], s);   hh[3] = cvt1(r[2*ks][3], s);
    hh[4] = cvt1(r[2*ks+1][0], s); hh[5] = cvt1(r[2*ks+1][1], s);
    hh[6] = cvt1(r[2*ks+1][2], s); hh[7] = cvt1(r[2*ks+1][3], s);
    h[ks] = hh;
  }
  s += __shfl_xor(s, 16);
  s += __shfl_xor(s, 32);
  hnorm = -HALF_LOG2E * s;
}

__global__ __launch_bounds__(256, 3) void gauss_gram_kernel(
    const float* __restrict__ X, float* __restrict__ K, int n) {
  const int lane = threadIdx.x & 63;
  const int wid  = threadIdx.x >> 6;   // 4 waves: 2x2, wave tile 64 rows x 32 cols
  const int wr = wid >> 1;             // 0..1 (row half of 128-row block)
  const int wc = wid & 1;              // 0..1 (col half of 64-col tile)
  const int l15 = lane & 15;
  const int lq  = lane >> 4;           // 0..3
  const int r8  = lane >> 3;           // 0..7 (transpose-read row in group)
  const int e8  = lane & 7;            // 0..7 (transpose-read col chunk)

  // Per-wave private transpose buffer: 32 rows x LROW floats (wave-synchronous).
  __shared__ float tbuf[4][32 * LROW];
  float* buf = tbuf[wid];

  const int i0     = blockIdx.x * 128 + wr * 64;   // output row base (this wave)
  const int jstrip = blockIdx.y * (64 * JT);       // column strip base (512 cols)
  const int jw     = wc * 32;                      // wave col offset within tile

  // ---- prologue: issue A loads, then B(jt=0) loads; cvt A while B flies ----
  f32x4 araw[4][4];
#pragma unroll
  for (int mi = 0; mi < 4; ++mi)
    issue_row(X, i0 + mi * 16 + l15, lq, araw[mi]);

  f32x4 braw[2][4];
#pragma unroll
  for (int ni = 0; ni < 2; ++ni)
    issue_row(X, jstrip + jw + ni * 16 + l15, lq, braw[ni]);

  s16x8 a[4][2]; float hA[4];
#pragma unroll
  for (int mi = 0; mi < 4; ++mi)
    cvt_row(araw[mi], a[mi], hA[mi]);
  // hA[mi] at lane l is -c*||row (i0+mi*16+l15)||^2 == this lane's output row.

#pragma unroll
  for (int jt = 0; jt < JT; ++jt) {
    const int j0 = jstrip + jt * 64 + jw;

    // ---- cvt current B (waits only on braw loads, older than any stores) ----
    s16x8 b[2][2]; float hcol[2][4];
#pragma unroll
    for (int ni = 0; ni < 2; ++ni) {
      float hB;
      cvt_row(braw[ni], b[ni], hB);
#pragma unroll
      for (int r = 0; r < 4; ++r)
        hcol[ni][r] = __shfl(hB, lq * 4 + r);   // -c*norm of col j0+ni*16+lq*4+r
    }

    // ---- prefetch next tile's B (issued ahead of this tile's stores) ----
    if (jt + 1 < JT) {
#pragma unroll
      for (int ni = 0; ni < 2; ++ni)
        issue_row(X, jstrip + (jt + 1) * 64 + jw + ni * 16 + l15, lq, braw[ni]);
    }
    // Pin VMEM order only: prefetch loads stay above the stores below.
    __builtin_amdgcn_sched_barrier(0x1 | 0x2 | 0x4 | 0x8);

    // ---- MFMA, swapped operands: lane's 4 acc regs = 4 consecutive cols ----
    f32x4 acc[4][2] = {};
#pragma unroll
    for (int ks = 0; ks < 2; ++ks)
#pragma unroll
      for (int mi = 0; mi < 4; ++mi)
#pragma unroll
        for (int ni = 0; ni < 2; ++ni)
          acc[mi][ni] = __builtin_amdgcn_mfma_f32_16x16x32_bf16(
              b[ni][ks], a[mi][ks], acc[mi][ni], 0, 0, 0);

    // Does this 64x32 tile touch the diagonal? (uniform branch)
    const bool diag = (i0 < j0 + 32) && (j0 < i0 + 64);

    // ---- epilogue: two 32-row passes; exp -> LDS transpose -> full-line stores ----
#pragma unroll
    for (int p = 0; p < 2; ++p) {
#pragma unroll
      for (int mh = 0; mh < 2; ++mh) {
        const int mi = p * 2 + mh;
        const int rg = i0 + mi * 16 + l15;
#pragma unroll
        for (int ni = 0; ni < 2; ++ni) {
          const int c0 = j0 + ni * 16 + lq * 4;
          f32x4 v;
          if (diag) {
#pragma unroll
            for (int r = 0; r < 4; ++r) {
              float arg = hA[mi] + hcol[ni][r] + LOG2E * acc[mi][ni][r];
              float e = exp2f(arg);
              v[r] = (rg == c0 + r) ? 1.0f : e;   // exact diagonal
            }
          } else {
#pragma unroll
            for (int r = 0; r < 4; ++r) {
              float arg = hA[mi] + hcol[ni][r] + LOG2E * acc[mi][ni][r];
              v[r] = exp2f(arg);
            }
          }
          *reinterpret_cast<f32x4*>(
              buf + (mh * 16 + l15) * LROW + ni * 16 + lq * 4) = v;
        }
      }
      // transpose-read: 8 lanes x 16B = 128B full line per row, 8 rows/instr
#pragma unroll
      for (int g = 0; g < 4; ++g) {
        f32x4 t = *reinterpret_cast<const f32x4*>(
            buf + (g * 8 + r8) * LROW + e8 * 4);
        const int rg = i0 + p * 32 + g * 8 + r8;
        *reinterpret_cast<f32x4*>(K + (size_t)rg * n + j0 + e8 * 4) = t;
      }
    }
  }
}

extern "C" void kernel_launch(void* const* d_in, const int* in_sizes, int n_in,
                              void* d_out, int out_size, void* d_ws, size_t ws_size,
                              hipStream_t stream) {
  (void)n_in; (void)d_ws; (void)ws_size; (void)out_size;
  const float* X = (const float*)d_in[0];
  float* K = (float*)d_out;
  const int n = in_sizes[0] / DDIM;          // 16384
  dim3 grid(n / 128, n / (64 * JT));         // (128, 32)
  gauss_gram_kernel<<<grid, 256, 0, stream>>>(X, K, n);
}